// Round 1
// baseline (103.396 us; speedup 1.0000x reference)
//
#include <hip/hip_runtime.h>

#define NSAMP 2048
#define NCONF 128
#define NMO   64
#define NE    16   // electrons per spin (matrix dim)

// One thread computes det(up) * det(dn) for one (sample, config) pair.
// 16x16 matrix held entirely in registers; Householder QR (pivot-free,
// unconditionally stable); det(A) = (-1)^15 * prod(alpha_k) * A[15][15].
__global__ __launch_bounds__(256, 1)
void SlaterPooling_45543833207162_kernel(const float* __restrict__ x,
                                         const int*   __restrict__ cup,
                                         const int*   __restrict__ cdn,
                                         float*       __restrict__ out) {
  const int g = blockIdx.x * 256 + threadIdx.x;   // g in [0, 2048*128)
  const int s = g >> 7;                           // sample
  const int c = g & 127;                          // config
  const float* xs = x + (size_t)s * (2 * NE * NMO);

  float result = 1.0f;

  // spin loop NOT unrolled: the two 256-float matrices reuse one register set
#pragma unroll 1
  for (int spin = 0; spin < 2; ++spin) {
    const int*   cfg  = (spin ? cdn : cup) + c * NE;
    const float* base = xs + spin * (NE * NMO);

    int col[NE];
#pragma unroll
    for (int j = 0; j < NE; ++j) col[j] = cfg[j];

    float A[NE][NE];
#pragma unroll
    for (int i = 0; i < NE; ++i) {
      const float* row = base + i * NMO;
#pragma unroll
      for (int j = 0; j < NE; ++j) A[i][j] = row[col[j]];
    }

    // Householder QR; only the trailing submatrix is ever updated.
    float det = -1.0f;  // (-1)^15 from 15 reflectors
#pragma unroll
    for (int k = 0; k < NE - 1; ++k) {
      // squared norm of column k, rows k..15
      float s2 = A[k][k] * A[k][k];
#pragma unroll
      for (int i = k + 1; i < NE; ++i) s2 = fmaf(A[i][k], A[i][k], s2);
      const float nrm   = __builtin_amdgcn_sqrtf(s2);
      const float akk   = A[k][k];
      const float alpha = (akk >= 0.0f) ? -nrm : nrm;   // R_kk
      const float vk    = akk - alpha;                  // |vk| = |akk|+nrm, no cancellation
      const float vtv   = 2.0f * fmaf(-alpha, akk, s2); // v^T v = 2(s2 - alpha*akk) >= 0
      const float tau   = 2.0f * __builtin_amdgcn_rcpf(vtv);
      det *= alpha;
#pragma unroll
      for (int j = k + 1; j < NE; ++j) {
        // w = v^T A[:,j]  (v_k = vk, v_i = A[i][k] for i>k)
        float w = vk * A[k][j];
#pragma unroll
        for (int i = k + 1; i < NE; ++i) w = fmaf(A[i][k], A[i][j], w);
        w *= tau;
        // update rows i>k only; row k and column k are never read again
#pragma unroll
        for (int i = k + 1; i < NE; ++i) A[i][j] = fmaf(-w, A[i][k], A[i][j]);
      }
    }
    det *= A[NE - 1][NE - 1];
    result *= det;
  }

  out[g] = result;   // out[s*128 + c]
}

extern "C" void kernel_launch(void* const* d_in, const int* in_sizes, int n_in,
                              void* d_out, int out_size, void* d_ws, size_t ws_size,
                              hipStream_t stream) {
  const float* x   = (const float*)d_in[0];
  const int*   cup = (const int*)d_in[1];
  const int*   cdn = (const int*)d_in[2];
  float*       out = (float*)d_out;

  const int total  = NSAMP * NCONF;            // 262144 threads, 1 det-pair each
  dim3 grid(total / 256), block(256);
  hipLaunchKernelGGL(SlaterPooling_45543833207162_kernel, grid, block, 0, stream,
                     x, cup, cdn, out);
}